// Round 9
// baseline (765.123 us; speedup 1.0000x reference)
//
#include <hip/hip_runtime.h>

// Problem constants (fixed by reference setup_inputs)
#define BATCH 2
#define L_SEQ 768
#define NH 12
#define DH 64
#define ND 8
#define EMB 768
#define RSQRT8 0.35355339059327373f

// ws layout (floats). Total 6,046,480 floats = 24.2 MB -- UNCHANGED footprint.
#define OFF_Q    0
#define OFF_K    1179648
#define OFF_V    2359296
#define OFF_L    3538944   // linv[bh][q][d] = 1/S : 147456
#define OFF_PART 3686400   // partial stats [bh*8+d][st*4+kq][q]: 2359296
#define OFF_P2   6045696   // per-(b,d,h) stat sums [bd][h][st]: 768
#define OFF_W    6046464   // weights [b][d]: 16

// ---------------------------------------------------------------------------
// K1 v4 (round-16): PIPE-SPLIT projection -- zero LDS, zero barriers.
// ROUND-15 LESSON: launch_bounds(256,4) did NOT stop the spill (VGPR still
// 64, WRITE still 305MB): the 2nd arg is only an occupancy FLOOR; the
// compiler minimizes VGPRs and spilled anyway. Deeper: redoing the pipe
// arithmetic, the ORIGINAL k1 (106us) was DS-READ-BOUND: 2 ds_read_b128/kk
// x 64kk x 12 chunks x 13.5 waves/CU x 12cy ~= 248Kcy/CU = 103us. Staging
// tweaks can't beat that; the DS instructions must go.
// FIX = port k45-v6's proven structure: lane = m-row, hs k-chunk in VGPRs
// (kv[64], live ~90 < 128); W streamed on the SCALAR pipe (wave-uniform
// 8-col slice, s_load_dwordx8 per kk, readfirstlane-forced); 8 FMA per kk
// with SGPR operand. Each wave owns 8 output cols over FULL k -> no LDS,
// no barrier, no reduce. FMA order k-ascending 0..767 per (m,n) = bitwise
// identical to original. Block 64m x 32n, grid 1728 (6.75 blk/CU), XCD
// swizzle (1728 = 8x216, bijective). fp32 VALU roofline = 34.6us.
// Verification: LDS_Block_Size=0, WRITE~15MB, VGPR~90-110, VALUBusy>=65%.
// ---------------------------------------------------------------------------
__global__ __launch_bounds__(256, 4) void k1_qkv(
    const float* __restrict__ hs,
    const float* __restrict__ Wq, const float* __restrict__ bq,
    const float* __restrict__ Wk, const float* __restrict__ bk,
    const float* __restrict__ Wv, const float* __restrict__ bvp,
    float* __restrict__ qw, float* __restrict__ kw, float* __restrict__ vw)
{
    const int tid = threadIdx.x;
    const int lane = tid & 63;
    // XCD-chunked bijective swizzle: 1728 = 8 * 216
    const int lb = (blockIdx.x & 7) * 216 + (blockIdx.x >> 3);
    const int gz = lb / 576;                 // 0..2 : q/k/v
    const int r2 = lb % 576;
    const int by = r2 / 24;                  // m-tile (64 rows), 0..23
    const int bx = r2 % 24;                  // n-tile (32 cols), 0..23

    const float* W    = (gz == 0) ? Wq : (gz == 1 ? Wk : Wv);
    const float* bias = (gz == 0) ? bq : (gz == 1 ? bk : bvp);
    float* dst        = (gz == 0) ? qw : (gz == 1 ? kw : vw);

    // wave-uniform 8-col slice (forced to SGPR)
    const int n0 = __builtin_amdgcn_readfirstlane(bx * 32 + (tid >> 6) * 8);

    const int m = by * 64 + lane;            // global row (never crosses batch)
    const int b2 = m / L_SEQ, l = m % L_SEQ;
    const float* hsrow = &hs[(size_t)m * EMB];

    float acc[8];
#pragma unroll
    for (int j = 0; j < 8; j++) acc[j] = 0.f;

#pragma unroll 1
    for (int c = 0; c < 12; c++) {
        const int kb = c * 64;
        // hs k-chunk -> VGPRs (must stay resident; live set ~90 < 128)
        float kv[64];
#pragma unroll
        for (int t = 0; t < 16; t++)
            *(float4*)&kv[t * 4] = *(const float4*)&hsrow[kb + t * 4];
        // W rows via scalar pipe: per kk one uniform 8-float slice
#pragma unroll 8
        for (int kk = 0; kk < 64; kk++) {
            const float* wr = &W[(size_t)(kb + kk) * EMB + n0];
#pragma unroll
            for (int j = 0; j < 8; j++)
                acc[j] = fmaf(kv[kk], wr[j], acc[j]);
        }
    }

    // epilogue: bias + store (2 x b128 per lane; dh0 is a multiple of 8)
    const int h = n0 >> 6;                   // head
    const int dh0 = n0 & 63;
    float o[8];
#pragma unroll
    for (int j = 0; j < 8; j++) o[j] = acc[j] + bias[n0 + j];
    float* op = &dst[((size_t)(b2 * NH + h) * L_SEQ + l) * DH + dh0];
    *(float4*)&op[0] = *(float4*)&o[0];
    *(float4*)&op[4] = *(float4*)&o[4];
}

// ---------------------------------------------------------------------------
// K2 v2 (round-14): K-chunk c+1 register-prefetched during compute of c.
// XCD-chunked bijective swizzle kept from round-13.
// ---------------------------------------------------------------------------
__global__ __launch_bounds__(256) void k2_stats(
    const float* __restrict__ qw, const float* __restrict__ kw,
    const float* __restrict__ mask, float* __restrict__ part)
{
    __shared__ float k_lds[64 * 64];
    __shared__ float m_lds[64];
    const int tid = threadIdx.x;
    const int lane = tid & 63, w = tid >> 6;
    const int qr = lane >> 3, d = lane & 7;
    const int lb = (blockIdx.x & 7) * 144 + (blockIdx.x >> 3);
    const int kq = lb & 3;
    const int t2 = lb >> 2;             // 0..287
    const int bh = t2 / 12;
    const int q0 = (t2 % 12) * 64;
    const int b = bh / NH;
    const int qw0 = q0 + w * 16;

    float qf[2][8];
#pragma unroll
    for (int qq = 0; qq < 2; qq++) {
        const float* qp = &qw[((size_t)bh * L_SEQ + qw0 + qr + qq * 8) * DH + d * 8];
        *(float4*)&qf[qq][0] = *(const float4*)qp;
        *(float4*)&qf[qq][4] = *(const float4*)(qp + 4);
    }
    float S[2] = {0.f, 0.f}, T2[2] = {0.f, 0.f}, SL[2] = {0.f, 0.f};
    float M[2] = {-1e30f, -1e30f};

    const int kb0 = kq * 192;

    // prefetch chunk 0
    float4 pk[4];
    float pm = 0.f;
    {
        const float* src = &kw[((size_t)bh * L_SEQ + kb0) * DH];
#pragma unroll
        for (int i = 0; i < 4; i++) pk[i] = *(const float4*)&src[(tid + 256 * i) * 4];
        if (tid < 64) pm = mask[b * L_SEQ + kb0 + tid];
    }

    for (int c = 0; c < 3; c++) {
        __syncthreads();
        {
#pragma unroll
            for (int i = 0; i < 4; i++)
                *(float4*)&k_lds[(tid + 256 * i) * 4] = pk[i];
            if (tid < 64) m_lds[tid] = pm;
        }
        __syncthreads();
        if (c < 2) {
            const int kb = kb0 + (c + 1) * 64;
            const float* src = &kw[((size_t)bh * L_SEQ + kb) * DH];
#pragma unroll
            for (int i = 0; i < 4; i++) pk[i] = *(const float4*)&src[(tid + 256 * i) * 4];
            if (tid < 64) pm = mask[b * L_SEQ + kb + tid];
        }
#pragma unroll 4
        for (int kk = 0; kk < 64; kk++) {
            float kv[8];
            *(float4*)&kv[0] = *(const float4*)&k_lds[kk * 64 + d * 8];
            *(float4*)&kv[4] = *(const float4*)&k_lds[kk * 64 + d * 8 + 4];
            float mval = m_lds[kk];
#pragma unroll
            for (int qq = 0; qq < 2; qq++) {
                float s = 0.f;
#pragma unroll
                for (int t = 0; t < 8; t++) s = fmaf(qf[qq][t], kv[t], s);
                s = fmaf(s, RSQRT8, mval);
                float e = __expf(s);
                S[qq] += e;
                T2[qq] = fmaf(e, e, T2[qq]);
                SL[qq] = fmaf(s, e, SL[qq]);
                M[qq] = fmaxf(M[qq], s);
            }
        }
    }
#pragma unroll
    for (int qq = 0; qq < 2; qq++) {
        int q = qw0 + qr + qq * 8;
        size_t base = (size_t)(bh * 8 + d) * 16;
        part[(base + 0 + kq) * 768 + q] = S[qq];
        part[(base + 4 + kq) * 768 + q] = T2[qq];
        part[(base + 8 + kq) * 768 + q] = SL[qq];
        part[(base + 12 + kq) * 768 + q] = M[qq];
    }
}

// ---------------------------------------------------------------------------
// K3a: per-(b,d,h) combine of k-quarters -> row stats -> linv + stat sums.
// Stores 1/S in [bh][q][d] layout so k45 fetches all 8 d-values for a q row
// with one uniform (scalar) 8-float load.
// ---------------------------------------------------------------------------
__global__ __launch_bounds__(256) void k3_reduce(
    const float* __restrict__ part, float* __restrict__ linv,
    float* __restrict__ part2)
{
    const int bdh = blockIdx.x;         // ((b*8+d)*12+h)
    const int bd = bdh / 12, h = bdh % 12;
    const int b = bd >> 3, d = bd & 7;
    const int bh = b * NH + h;
    const int tid = threadIdx.x;
    const int lane = tid & 63, wave = tid >> 6;
    const size_t base = (size_t)(bh * 8 + d) * 16;
    float acc[4] = {0.f, 0.f, 0.f, 0.f};

    for (int q = tid; q < 768; q += 256) {
        float Sv = 0.f, T2v = 0.f, SLv = 0.f, Mv = -1e30f;
#pragma unroll
        for (int kq = 0; kq < 4; kq++) {
            Sv  += part[(base + 0 + kq) * 768 + q];
            T2v += part[(base + 4 + kq) * 768 + q];
            SLv += part[(base + 8 + kq) * 768 + q];
            Mv = fmaxf(Mv, part[(base + 12 + kq) * 768 + q]);
        }
        float inv = 1.0f / Sv;
        linv[((size_t)bh * 768 + q) * 8 + d] = inv;
        float hhi = T2v * inv * inv;
        float maxp = __expf(Mv) * inv;
        float ent = __logf(Sv) - SLv * inv;
        float var = (hhi - (1.0f / 768.0f)) * (1.0f / 767.0f);
        acc[0] += var; acc[1] += maxp; acc[2] += ent; acc[3] += hhi;
    }
    __shared__ float red[4][4];
#pragma unroll
    for (int st = 0; st < 4; st++) {
        float a = acc[st];
#pragma unroll
        for (int off = 32; off > 0; off >>= 1) a += __shfl_xor(a, off, 64);
        acc[st] = a;
    }
    if (lane == 0) {
#pragma unroll
        for (int st = 0; st < 4; st++) red[wave][st] = acc[st];
    }
    __syncthreads();
    if (tid == 0) {
#pragma unroll
        for (int st = 0; st < 4; st++)
            part2[(size_t)(bd * 12 + h) * 4 + st] =
                red[0][st] + red[1][st] + red[2][st] + red[3][st];
    }
}

// ---------------------------------------------------------------------------
// K3b: sum over h, min-max norm over d, softmax(2.5*score) -> weights[b][d].
// ---------------------------------------------------------------------------
__global__ __launch_bounds__(64) void k3_weights(
    const float* __restrict__ part2, float* __restrict__ wgt)
{
    __shared__ float stats_l[64];       // [b][d][st]
    const int tid = threadIdx.x;
    {
        const int bd = tid >> 2, st = tid & 3;
        float s = 0.f;
#pragma unroll
        for (int h = 0; h < 12; h++) s += part2[(size_t)(bd * 12 + h) * 4 + st];
        stats_l[tid] = s * (1.0f / 9216.0f);
    }
    __syncthreads();
    if (tid == 0) {
        for (int b = 0; b < BATCH; b++) {
            float v[4][8];
            for (int st = 0; st < 4; st++)
                for (int d = 0; d < 8; d++) v[st][d] = stats_l[(b * 8 + d) * 4 + st];
            float nrm[4][8];
            for (int st = 0; st < 4; st++) {
                float mn = v[st][0], mx = v[st][0];
                for (int d = 1; d < 8; d++) { mn = fminf(mn, v[st][d]); mx = fmaxf(mx, v[st][d]); }
                float rng = fmaxf(mx - mn, 1e-12f);
                for (int d = 0; d < 8; d++) nrm[st][d] = (v[st][d] - mn) / rng;
            }
            float sc[8];
            for (int d = 0; d < 8; d++)
                sc[d] = 0.5f * nrm[0][d] + 0.3f * nrm[1][d] + 0.2f * nrm[3][d] - 0.4f * nrm[2][d];
            float m = 2.5f * sc[0];
            for (int d = 1; d < 8; d++) m = fmaxf(m, 2.5f * sc[d]);
            float e8[8]; float ssum = 0.f;
            for (int d = 0; d < 8; d++) { e8[d] = __expf(2.5f * sc[d] - m); ssum += e8[d]; }
            for (int d = 0; d < 8; d++) wgt[b * ND + d] = e8[d] / ssum;
        }
    }
}

// ---------------------------------------------------------------------------
// K45 v6 (round-13, UNCHANGED): pipe-split a4+ctx with register-resident K.
// ---------------------------------------------------------------------------
__global__ __launch_bounds__(256, 4) void k45_fused(
    const float* __restrict__ qw, const float* __restrict__ kw,
    const float* __restrict__ vw, const float* __restrict__ mask,
    const float* __restrict__ linv, const float* __restrict__ wgt,
    float* __restrict__ out_a4, float* __restrict__ out_ctx)
{
    // per-wave region: a4T [k 64][20 pad] during chunks; ctx [q 16][68 pad] at end
    __shared__ float smem[4][64 * 20];
    const int tid = threadIdx.x;
    const int lane = tid & 63, w = tid >> 6;
    // XCD-chunked bijective swizzle: logical blocks 0..143 -> XCD0, etc.
    const int lb = (blockIdx.x & 7) * 144 + (blockIdx.x >> 3);
    const int bh = lb / 48;                 // 0..23
    const int q0 = (lb % 48) * 16;
    const int b = bh / NH, h = bh % NH;
    // phase-B lane mapping: 4 q rows (qg*4..+3) x 4 dh cols (dhl*4..+3)
    const int qg = lane >> 4;               // 0..3
    const int dhl = lane & 15;              // 0..15

    const float* kbase = &kw[(size_t)bh * L_SEQ * DH];
    const float* vbase = &vw[(size_t)bh * L_SEQ * DH];
    const float* qtile = &qw[((size_t)bh * L_SEQ + q0) * DH];   // block-uniform rows
    const float* ltile = &linv[((size_t)bh * L_SEQ + q0) * 8];

    // wgt[b][0..7]: broadcast
    float wv[8];
#pragma unroll
    for (int d = 0; d < 8; d++) wv[d] = wgt[b * ND + d];

    float acc[4][4];                        // ctx partial: 4 q rows x 4 dh
#pragma unroll
    for (int i = 0; i < 4; i++)
#pragma unroll
        for (int j = 0; j < 4; j++) acc[i][j] = 0.f;

    float* sm = &smem[w][0];

    for (int c = 0; c < 3; c++) {
        const int kb = (w * 3 + c) * 64;    // this wave's k chunk
        const int krow = kb + lane;

        // K row -> VGPRs (must stay resident: see header comment)
        float kv[64];
        {
            const float* kp = &kbase[(size_t)krow * DH];
#pragma unroll
            for (int t = 0; t < 16; t++)
                *(float4*)&kv[t * 4] = *(const float4*)&kp[t * 4];
        }
        const float mval = mask[b * L_SEQ + krow];

        // ---- Phase A: a4(q, krow), one q at a time, K register-resident ----
#pragma unroll 2
        for (int q = 0; q < 16; q++) {
            const float* qp = &qtile[(size_t)q * DH];
            const float* lp = &ltile[(size_t)q * 8];
            float sd[8];
#pragma unroll
            for (int d = 0; d < 8; d++) sd[d] = 0.f;
#pragma unroll
            for (int d = 0; d < 8; d++)
#pragma unroll
                for (int t = 0; t < 8; t++)
                    sd[d] = fmaf(qp[d * 8 + t], kv[d * 8 + t], sd[d]);
            float a4v = 0.f;
#pragma unroll
            for (int d = 0; d < 8; d++) {
                float sv = fmaf(sd[d], RSQRT8, mval);
                a4v = fmaf(wv[d] * lp[d], __expf(sv), a4v);
            }
            out_a4[((size_t)bh * L_SEQ + q0 + q) * L_SEQ + krow] = a4v;
            sm[lane * 20 + q] = a4v;        // a4T[k][q] (wave-private)
        }

        // ---- Phase B: ctx += a4T @ V over this chunk (k ascending) ----
        const float* vrow = &vbase[(size_t)kb * DH + dhl * 4];
#pragma unroll 8
        for (int k = 0; k < 64; k++) {
            float av[4];
            *(float4*)av = *(const float4*)&sm[k * 20 + qg * 4];
            float4 vv = *(const float4*)&vrow[(size_t)k * DH];
#pragma unroll
            for (int i = 0; i < 4; i++) {
                acc[i][0] = fmaf(av[i], vv.x, acc[i][0]);
                acc[i][1] = fmaf(av[i], vv.y, acc[i][1]);
                acc[i][2] = fmaf(av[i], vv.z, acc[i][2]);
                acc[i][3] = fmaf(av[i], vv.w, acc[i][3]);
            }
        }
    }

    // ---- ctx k-partials -> LDS (alias a4T region), block-reduce over waves ----
#pragma unroll
    for (int i = 0; i < 4; i++)
        *(float4*)&sm[(qg * 4 + i) * 68 + dhl * 4] = *(float4*)&acc[i][0];
    __syncthreads();
    {
        const int q = tid >> 4;             // 0..15
        const int dh4 = (tid & 15) * 4;     // 0..60
        float r[4] = {0.f, 0.f, 0.f, 0.f};
#pragma unroll
        for (int ww = 0; ww < 4; ww++) {
            const float* s2 = &smem[ww][q * 68 + dh4];
#pragma unroll
            for (int j = 0; j < 4; j++) r[j] += s2[j];
        }
        *(float4*)&out_ctx[((size_t)b * L_SEQ + q0 + q) * EMB + h * DH + dh4] =
            *(float4*)r;
    }
}

// ---------------------------------------------------------------------------
extern "C" void kernel_launch(void* const* d_in, const int* in_sizes, int n_in,
                              void* d_out, int out_size, void* d_ws, size_t ws_size,
                              hipStream_t stream)
{
    const float* hs   = (const float*)d_in[0];
    const float* mask = (const float*)d_in[1];
    const float* Wq   = (const float*)d_in[2];
    const float* bq   = (const float*)d_in[3];
    const float* Wk   = (const float*)d_in[4];
    const float* bk   = (const float*)d_in[5];
    const float* Wv   = (const float*)d_in[6];
    const float* bv   = (const float*)d_in[7];

    float* ws = (float*)d_ws;
    float* qw    = ws + OFF_Q;
    float* kw    = ws + OFF_K;
    float* vw    = ws + OFF_V;
    float* linv  = ws + OFF_L;
    float* part  = ws + OFF_PART;
    float* part2 = ws + OFF_P2;
    float* wgt   = ws + OFF_W;

    float* out_ctx = (float*)d_out;                                  // [B, L, 768]
    float* out_a4  = (float*)d_out + (size_t)BATCH * L_SEQ * EMB;    // [B, H, L, L]

    k1_qkv<<<dim3(1728), 256, 0, stream>>>(hs, Wq, bq, Wk, bk, Wv, bv, qw, kw, vw);
    k2_stats<<<dim3(1152), 256, 0, stream>>>(qw, kw, mask, part);
    k3_reduce<<<dim3(192), 256, 0, stream>>>(part, linv, part2);
    k3_weights<<<dim3(1), 64, 0, stream>>>(part2, wgt);
    k45_fused<<<dim3(1152), 256, 0, stream>>>(qw, kw, vw, mask, linv, wgt,
                                              out_a4, out_ctx);
}

// Round 10
// 418.501 us; speedup vs baseline: 1.8282x; 1.8282x over previous
//
#include <hip/hip_runtime.h>

// Problem constants (fixed by reference setup_inputs)
#define BATCH 2
#define L_SEQ 768
#define NH 12
#define DH 64
#define ND 8
#define EMB 768
#define RSQRT8 0.35355339059327373f

// ws layout (floats). Total 6,046,480 floats = 24.2 MB -- UNCHANGED footprint.
#define OFF_Q    0
#define OFF_K    1179648
#define OFF_V    2359296
#define OFF_L    3538944   // linv[bh][q][d] = 1/S : 147456
#define OFF_PART 3686400   // partial stats [bh*8+d][st*4+kq][q]: 2359296
#define OFF_P2   6045696   // per-(b,d,h) stat sums [bd][h][st]: 768
#define OFF_W    6046464   // weights [b][d]: 16

// ---------------------------------------------------------------------------
// K1 v5 (round-17): ZERO-LDS 4x4-tile GEMM, both operands streamed from
// global (VMEM pipe), NO per-thread arrays.
// ROUND-16 LESSON: kv[64] spilled AGAIN (VGPR 40, 2GB scratch traffic) --
// this compiler will not keep a big per-thread array resident; stop trying.
// ROUND-15/16 ARITHMETIC: original k1 (106us) is DS-bound (2 b128/kk/wave
// x 768kk x 13.5 waves/CU x 12cy = 104us). Per kk each thread needs only
// 4 A floats (ty-broadcast: 4 distinct 16B addrs/wave) + 4 B floats
// (tx-coalesced 256B line, L1-hit, shared by all 4 waves) -> serve BOTH
// from global/L1. DS instr = 0, barriers = 0, max live ~80 regs (no spill
// motive). VMEM floor ~35us overlapping VALU floor 35us.
// Per-kk FMA order (kk ascending, i outer, j inner) BITWISE-IDENTICAL to
// the round-6 original -> absmax unchanged.
// Verification: LDS_Block_Size=0, WRITE~15MB, VGPR 60-84, VALUBusy>=55%.
// ---------------------------------------------------------------------------
__global__ __launch_bounds__(256) void k1_qkv(
    const float* __restrict__ hs,
    const float* __restrict__ Wq, const float* __restrict__ bq,
    const float* __restrict__ Wk, const float* __restrict__ bk,
    const float* __restrict__ Wv, const float* __restrict__ bvp,
    float* __restrict__ qw, float* __restrict__ kw, float* __restrict__ vw)
{
    const int tid = threadIdx.x;
    const int tx = tid & 15, ty = tid >> 4;
    const int bx = blockIdx.x, by = blockIdx.y, gz = blockIdx.z;
    const float* W    = (gz == 0) ? Wq : (gz == 1 ? Wk : Wv);
    const float* bias = (gz == 0) ? bq : (gz == 1 ? bk : bvp);
    float* dst        = (gz == 0) ? qw : (gz == 1 ? kw : vw);

    const int ldc = tx * 4;
    const float* a0 = &hs[(size_t)(by * 64 + ty * 4 + 0) * EMB];
    const float* a1 = &hs[(size_t)(by * 64 + ty * 4 + 1) * EMB];
    const float* a2r = &hs[(size_t)(by * 64 + ty * 4 + 2) * EMB];
    const float* a3 = &hs[(size_t)(by * 64 + ty * 4 + 3) * EMB];
    const float* Wc = &W[bx * 64 + ldc];

    float acc[4][4];
#pragma unroll
    for (int i = 0; i < 4; i++)
#pragma unroll
        for (int j = 0; j < 4; j++) acc[i][j] = 0.f;

#pragma unroll 2
    for (int k4 = 0; k4 < 192; k4++) {
        const int kk = k4 * 4;
        // A frags: 4 rows x 4 k (broadcast: 4 distinct 16B addrs per wave)
        float a[4][4];
        *(float4*)&a[0][0] = *(const float4*)&a0[kk];
        *(float4*)&a[1][0] = *(const float4*)&a1[kk];
        *(float4*)&a[2][0] = *(const float4*)&a2r[kk];
        *(float4*)&a[3][0] = *(const float4*)&a3[kk];
        // B rows: per kk one coalesced 256B line across the wave (L1-hit)
#pragma unroll
        for (int u = 0; u < 4; u++) {
            float b[4];
            *(float4*)b = *(const float4*)&Wc[(size_t)(kk + u) * EMB];
#pragma unroll
            for (int i = 0; i < 4; i++)
#pragma unroll
                for (int j = 0; j < 4; j++)
                    acc[i][j] = fmaf(a[i][u], b[j], acc[i][j]);
        }
    }

#pragma unroll
    for (int i = 0; i < 4; i++) {
        int m = by * 64 + ty * 4 + i;
        int b2 = m / L_SEQ, l = m % L_SEQ;
        float o[4];
#pragma unroll
        for (int j = 0; j < 4; j++) o[j] = acc[i][j] + bias[bx * 64 + tx * 4 + j];
        *(float4*)&dst[((size_t)(b2 * NH + bx) * L_SEQ + l) * DH + tx * 4] = *(float4*)o;
    }
}

// ---------------------------------------------------------------------------
// K2 v2 (round-14): K-chunk c+1 register-prefetched during compute of c.
// XCD-chunked bijective swizzle kept from round-13.
// ---------------------------------------------------------------------------
__global__ __launch_bounds__(256) void k2_stats(
    const float* __restrict__ qw, const float* __restrict__ kw,
    const float* __restrict__ mask, float* __restrict__ part)
{
    __shared__ float k_lds[64 * 64];
    __shared__ float m_lds[64];
    const int tid = threadIdx.x;
    const int lane = tid & 63, w = tid >> 6;
    const int qr = lane >> 3, d = lane & 7;
    const int lb = (blockIdx.x & 7) * 144 + (blockIdx.x >> 3);
    const int kq = lb & 3;
    const int t2 = lb >> 2;             // 0..287
    const int bh = t2 / 12;
    const int q0 = (t2 % 12) * 64;
    const int b = bh / NH;
    const int qw0 = q0 + w * 16;

    float qf[2][8];
#pragma unroll
    for (int qq = 0; qq < 2; qq++) {
        const float* qp = &qw[((size_t)bh * L_SEQ + qw0 + qr + qq * 8) * DH + d * 8];
        *(float4*)&qf[qq][0] = *(const float4*)qp;
        *(float4*)&qf[qq][4] = *(const float4*)(qp + 4);
    }
    float S[2] = {0.f, 0.f}, T2[2] = {0.f, 0.f}, SL[2] = {0.f, 0.f};
    float M[2] = {-1e30f, -1e30f};

    const int kb0 = kq * 192;

    // prefetch chunk 0
    float4 pk[4];
    float pm = 0.f;
    {
        const float* src = &kw[((size_t)bh * L_SEQ + kb0) * DH];
#pragma unroll
        for (int i = 0; i < 4; i++) pk[i] = *(const float4*)&src[(tid + 256 * i) * 4];
        if (tid < 64) pm = mask[b * L_SEQ + kb0 + tid];
    }

    for (int c = 0; c < 3; c++) {
        __syncthreads();
        {
#pragma unroll
            for (int i = 0; i < 4; i++)
                *(float4*)&k_lds[(tid + 256 * i) * 4] = pk[i];
            if (tid < 64) m_lds[tid] = pm;
        }
        __syncthreads();
        if (c < 2) {
            const int kb = kb0 + (c + 1) * 64;
            const float* src = &kw[((size_t)bh * L_SEQ + kb) * DH];
#pragma unroll
            for (int i = 0; i < 4; i++) pk[i] = *(const float4*)&src[(tid + 256 * i) * 4];
            if (tid < 64) pm = mask[b * L_SEQ + kb + tid];
        }
#pragma unroll 4
        for (int kk = 0; kk < 64; kk++) {
            float kv[8];
            *(float4*)&kv[0] = *(const float4*)&k_lds[kk * 64 + d * 8];
            *(float4*)&kv[4] = *(const float4*)&k_lds[kk * 64 + d * 8 + 4];
            float mval = m_lds[kk];
#pragma unroll
            for (int qq = 0; qq < 2; qq++) {
                float s = 0.f;
#pragma unroll
                for (int t = 0; t < 8; t++) s = fmaf(qf[qq][t], kv[t], s);
                s = fmaf(s, RSQRT8, mval);
                float e = __expf(s);
                S[qq] += e;
                T2[qq] = fmaf(e, e, T2[qq]);
                SL[qq] = fmaf(s, e, SL[qq]);
                M[qq] = fmaxf(M[qq], s);
            }
        }
    }
#pragma unroll
    for (int qq = 0; qq < 2; qq++) {
        int q = qw0 + qr + qq * 8;
        size_t base = (size_t)(bh * 8 + d) * 16;
        part[(base + 0 + kq) * 768 + q] = S[qq];
        part[(base + 4 + kq) * 768 + q] = T2[qq];
        part[(base + 8 + kq) * 768 + q] = SL[qq];
        part[(base + 12 + kq) * 768 + q] = M[qq];
    }
}

// ---------------------------------------------------------------------------
// K3a: per-(b,d,h) combine of k-quarters -> row stats -> linv + stat sums.
// Stores 1/S in [bh][q][d] layout so k45 fetches all 8 d-values for a q row
// with one uniform (scalar) 8-float load.
// ---------------------------------------------------------------------------
__global__ __launch_bounds__(256) void k3_reduce(
    const float* __restrict__ part, float* __restrict__ linv,
    float* __restrict__ part2)
{
    const int bdh = blockIdx.x;         // ((b*8+d)*12+h)
    const int bd = bdh / 12, h = bdh % 12;
    const int b = bd >> 3, d = bd & 7;
    const int bh = b * NH + h;
    const int tid = threadIdx.x;
    const int lane = tid & 63, wave = tid >> 6;
    const size_t base = (size_t)(bh * 8 + d) * 16;
    float acc[4] = {0.f, 0.f, 0.f, 0.f};

    for (int q = tid; q < 768; q += 256) {
        float Sv = 0.f, T2v = 0.f, SLv = 0.f, Mv = -1e30f;
#pragma unroll
        for (int kq = 0; kq < 4; kq++) {
            Sv  += part[(base + 0 + kq) * 768 + q];
            T2v += part[(base + 4 + kq) * 768 + q];
            SLv += part[(base + 8 + kq) * 768 + q];
            Mv = fmaxf(Mv, part[(base + 12 + kq) * 768 + q]);
        }
        float inv = 1.0f / Sv;
        linv[((size_t)bh * 768 + q) * 8 + d] = inv;
        float hhi = T2v * inv * inv;
        float maxp = __expf(Mv) * inv;
        float ent = __logf(Sv) - SLv * inv;
        float var = (hhi - (1.0f / 768.0f)) * (1.0f / 767.0f);
        acc[0] += var; acc[1] += maxp; acc[2] += ent; acc[3] += hhi;
    }
    __shared__ float red[4][4];
#pragma unroll
    for (int st = 0; st < 4; st++) {
        float a = acc[st];
#pragma unroll
        for (int off = 32; off > 0; off >>= 1) a += __shfl_xor(a, off, 64);
        acc[st] = a;
    }
    if (lane == 0) {
#pragma unroll
        for (int st = 0; st < 4; st++) red[wave][st] = acc[st];
    }
    __syncthreads();
    if (tid == 0) {
#pragma unroll
        for (int st = 0; st < 4; st++)
            part2[(size_t)(bd * 12 + h) * 4 + st] =
                red[0][st] + red[1][st] + red[2][st] + red[3][st];
    }
}

// ---------------------------------------------------------------------------
// K3b: sum over h, min-max norm over d, softmax(2.5*score) -> weights[b][d].
// ---------------------------------------------------------------------------
__global__ __launch_bounds__(64) void k3_weights(
    const float* __restrict__ part2, float* __restrict__ wgt)
{
    __shared__ float stats_l[64];       // [b][d][st]
    const int tid = threadIdx.x;
    {
        const int bd = tid >> 2, st = tid & 3;
        float s = 0.f;
#pragma unroll
        for (int h = 0; h < 12; h++) s += part2[(size_t)(bd * 12 + h) * 4 + st];
        stats_l[tid] = s * (1.0f / 9216.0f);
    }
    __syncthreads();
    if (tid == 0) {
        for (int b = 0; b < BATCH; b++) {
            float v[4][8];
            for (int st = 0; st < 4; st++)
                for (int d = 0; d < 8; d++) v[st][d] = stats_l[(b * 8 + d) * 4 + st];
            float nrm[4][8];
            for (int st = 0; st < 4; st++) {
                float mn = v[st][0], mx = v[st][0];
                for (int d = 1; d < 8; d++) { mn = fminf(mn, v[st][d]); mx = fmaxf(mx, v[st][d]); }
                float rng = fmaxf(mx - mn, 1e-12f);
                for (int d = 0; d < 8; d++) nrm[st][d] = (v[st][d] - mn) / rng;
            }
            float sc[8];
            for (int d = 0; d < 8; d++)
                sc[d] = 0.5f * nrm[0][d] + 0.3f * nrm[1][d] + 0.2f * nrm[3][d] - 0.4f * nrm[2][d];
            float m = 2.5f * sc[0];
            for (int d = 1; d < 8; d++) m = fmaxf(m, 2.5f * sc[d]);
            float e8[8]; float ssum = 0.f;
            for (int d = 0; d < 8; d++) { e8[d] = __expf(2.5f * sc[d] - m); ssum += e8[d]; }
            for (int d = 0; d < 8; d++) wgt[b * ND + d] = e8[d] / ssum;
        }
    }
}

// ---------------------------------------------------------------------------
// K45 v6 (round-13, UNCHANGED): pipe-split a4+ctx with register-resident K.
// ---------------------------------------------------------------------------
__global__ __launch_bounds__(256, 4) void k45_fused(
    const float* __restrict__ qw, const float* __restrict__ kw,
    const float* __restrict__ vw, const float* __restrict__ mask,
    const float* __restrict__ linv, const float* __restrict__ wgt,
    float* __restrict__ out_a4, float* __restrict__ out_ctx)
{
    // per-wave region: a4T [k 64][20 pad] during chunks; ctx [q 16][68 pad] at end
    __shared__ float smem[4][64 * 20];
    const int tid = threadIdx.x;
    const int lane = tid & 63, w = tid >> 6;
    // XCD-chunked bijective swizzle: logical blocks 0..143 -> XCD0, etc.
    const int lb = (blockIdx.x & 7) * 144 + (blockIdx.x >> 3);
    const int bh = lb / 48;                 // 0..23
    const int q0 = (lb % 48) * 16;
    const int b = bh / NH, h = bh % NH;
    // phase-B lane mapping: 4 q rows (qg*4..+3) x 4 dh cols (dhl*4..+3)
    const int qg = lane >> 4;               // 0..3
    const int dhl = lane & 15;              // 0..15

    const float* kbase = &kw[(size_t)bh * L_SEQ * DH];
    const float* vbase = &vw[(size_t)bh * L_SEQ * DH];
    const float* qtile = &qw[((size_t)bh * L_SEQ + q0) * DH];   // block-uniform rows
    const float* ltile = &linv[((size_t)bh * L_SEQ + q0) * 8];

    // wgt[b][0..7]: broadcast
    float wv[8];
#pragma unroll
    for (int d = 0; d < 8; d++) wv[d] = wgt[b * ND + d];

    float acc[4][4];                        // ctx partial: 4 q rows x 4 dh
#pragma unroll
    for (int i = 0; i < 4; i++)
#pragma unroll
        for (int j = 0; j < 4; j++) acc[i][j] = 0.f;

    float* sm = &smem[w][0];

    for (int c = 0; c < 3; c++) {
        const int kb = (w * 3 + c) * 64;    // this wave's k chunk
        const int krow = kb + lane;

        // K row -> VGPRs (must stay resident: see header comment)
        float kv[64];
        {
            const float* kp = &kbase[(size_t)krow * DH];
#pragma unroll
            for (int t = 0; t < 16; t++)
                *(float4*)&kv[t * 4] = *(const float4*)&kp[t * 4];
        }
        const float mval = mask[b * L_SEQ + krow];

        // ---- Phase A: a4(q, krow), one q at a time, K register-resident ----
#pragma unroll 2
        for (int q = 0; q < 16; q++) {
            const float* qp = &qtile[(size_t)q * DH];
            const float* lp = &ltile[(size_t)q * 8];
            float sd[8];
#pragma unroll
            for (int d = 0; d < 8; d++) sd[d] = 0.f;
#pragma unroll
            for (int d = 0; d < 8; d++)
#pragma unroll
                for (int t = 0; t < 8; t++)
                    sd[d] = fmaf(qp[d * 8 + t], kv[d * 8 + t], sd[d]);
            float a4v = 0.f;
#pragma unroll
            for (int d = 0; d < 8; d++) {
                float sv = fmaf(sd[d], RSQRT8, mval);
                a4v = fmaf(wv[d] * lp[d], __expf(sv), a4v);
            }
            out_a4[((size_t)bh * L_SEQ + q0 + q) * L_SEQ + krow] = a4v;
            sm[lane * 20 + q] = a4v;        // a4T[k][q] (wave-private)
        }

        // ---- Phase B: ctx += a4T @ V over this chunk (k ascending) ----
        const float* vrow = &vbase[(size_t)kb * DH + dhl * 4];
#pragma unroll 8
        for (int k = 0; k < 64; k++) {
            float av[4];
            *(float4*)av = *(const float4*)&sm[k * 20 + qg * 4];
            float4 vv = *(const float4*)&vrow[(size_t)k * DH];
#pragma unroll
            for (int i = 0; i < 4; i++) {
                acc[i][0] = fmaf(av[i], vv.x, acc[i][0]);
                acc[i][1] = fmaf(av[i], vv.y, acc[i][1]);
                acc[i][2] = fmaf(av[i], vv.z, acc[i][2]);
                acc[i][3] = fmaf(av[i], vv.w, acc[i][3]);
            }
        }
    }

    // ---- ctx k-partials -> LDS (alias a4T region), block-reduce over waves ----
#pragma unroll
    for (int i = 0; i < 4; i++)
        *(float4*)&sm[(qg * 4 + i) * 68 + dhl * 4] = *(float4*)&acc[i][0];
    __syncthreads();
    {
        const int q = tid >> 4;             // 0..15
        const int dh4 = (tid & 15) * 4;     // 0..60
        float r[4] = {0.f, 0.f, 0.f, 0.f};
#pragma unroll
        for (int ww = 0; ww < 4; ww++) {
            const float* s2 = &smem[ww][q * 68 + dh4];
#pragma unroll
            for (int j = 0; j < 4; j++) r[j] += s2[j];
        }
        *(float4*)&out_ctx[((size_t)b * L_SEQ + q0 + q) * EMB + h * DH + dh4] =
            *(float4*)r;
    }
}

// ---------------------------------------------------------------------------
extern "C" void kernel_launch(void* const* d_in, const int* in_sizes, int n_in,
                              void* d_out, int out_size, void* d_ws, size_t ws_size,
                              hipStream_t stream)
{
    const float* hs   = (const float*)d_in[0];
    const float* mask = (const float*)d_in[1];
    const float* Wq   = (const float*)d_in[2];
    const float* bq   = (const float*)d_in[3];
    const float* Wk   = (const float*)d_in[4];
    const float* bk   = (const float*)d_in[5];
    const float* Wv   = (const float*)d_in[6];
    const float* bv   = (const float*)d_in[7];

    float* ws = (float*)d_ws;
    float* qw    = ws + OFF_Q;
    float* kw    = ws + OFF_K;
    float* vw    = ws + OFF_V;
    float* linv  = ws + OFF_L;
    float* part  = ws + OFF_PART;
    float* part2 = ws + OFF_P2;
    float* wgt   = ws + OFF_W;

    float* out_ctx = (float*)d_out;                                  // [B, L, 768]
    float* out_a4  = (float*)d_out + (size_t)BATCH * L_SEQ * EMB;    // [B, H, L, L]

    k1_qkv<<<dim3(12, 24, 3), 256, 0, stream>>>(hs, Wq, bq, Wk, bk, Wv, bv, qw, kw, vw);
    k2_stats<<<dim3(1152), 256, 0, stream>>>(qw, kw, mask, part);
    k3_reduce<<<dim3(192), 256, 0, stream>>>(part, linv, part2);
    k3_weights<<<dim3(1), 64, 0, stream>>>(part2, wgt);
    k45_fused<<<dim3(1152), 256, 0, stream>>>(qw, kw, vw, mask, linv, wgt,
                                              out_a4, out_ctx);
}

// Round 11
// 337.128 us; speedup vs baseline: 2.2695x; 1.2414x over previous
//
#include <hip/hip_runtime.h>

// Problem constants (fixed by reference setup_inputs)
#define BATCH 2
#define L_SEQ 768
#define NH 12
#define DH 64
#define ND 8
#define EMB 768
#define RSQRT8 0.35355339059327373f

// ws layout (floats). Total 6,046,480 floats = 24.2 MB -- UNCHANGED footprint.
#define OFF_Q    0
#define OFF_K    1179648
#define OFF_V    2359296
#define OFF_L    3538944   // linv[bh][q][d] = 1/S : 147456
#define OFF_PART 3686400   // partial stats [bh*8+d][st*4+kq][q]: 2359296
#define OFF_P2   6045696   // per-(b,d,h) stat sums [bd][h][st]: 768
#define OFF_W    6046464   // weights [b][d]: 16

// ---------------------------------------------------------------------------
// K1 v6 (round-18): HYBRID -- B (W) staged in LDS, A (hs) streamed from
// global; half the DS instructions of the proven 106us original.
// EVIDENCE LADDER: original = DS-bound 104us (2 DS b128/kk/wave, r-15 arith);
// all-VMEM v5 = latency wall 202us (VALUBusy 25%, 1536 VMEM/wave, VGPR 36);
// big per-thread arrays spill (r-16: kv[64] -> 2GB scratch); loop-carried
// prefetch regs spill (r-14/15: 305MB WRITE).
// HYBRID: B keeps the LDS path it needs for coalescing (1 DS b128/kk/wave ->
// DS floor 52us); A = 4-addr-broadcast float4 global loads, 4 per k4 group,
// hidden under the group's 64 FMAs (768 VMEM/wave, ~17us issue). No
// loop-carried prefetch, no arrays beyond acc+a (live ~70 VGPR, no spill
// motive). FMA order kk-ascending, i outer j inner = BITWISE-IDENTICAL.
// Verification: LDS_Block_Size 17408, WRITE ~14MB, VGPR ~70, dur 60-75us.
// ---------------------------------------------------------------------------
__global__ __launch_bounds__(256) void k1_qkv(
    const float* __restrict__ hs,
    const float* __restrict__ Wq, const float* __restrict__ bq,
    const float* __restrict__ Wk, const float* __restrict__ bk,
    const float* __restrict__ Wv, const float* __restrict__ bvp,
    float* __restrict__ qw, float* __restrict__ kw, float* __restrict__ vw)
{
    __shared__ float Bs[64][68];
    const int tid = threadIdx.x;
    const int tx = tid & 15, ty = tid >> 4;
    const int bx = blockIdx.x, by = blockIdx.y, gz = blockIdx.z;
    const float* W    = (gz == 0) ? Wq : (gz == 1 ? Wk : Wv);
    const float* bias = (gz == 0) ? bq : (gz == 1 ? bk : bvp);
    float* dst        = (gz == 0) ? qw : (gz == 1 ? kw : vw);

    const int ldc = tx * 4;
    const float* a0  = &hs[(size_t)(by * 64 + ty * 4 + 0) * EMB];
    const float* a1  = &hs[(size_t)(by * 64 + ty * 4 + 1) * EMB];
    const float* a2r = &hs[(size_t)(by * 64 + ty * 4 + 2) * EMB];
    const float* a3  = &hs[(size_t)(by * 64 + ty * 4 + 3) * EMB];

    float acc[4][4];
#pragma unroll
    for (int i = 0; i < 4; i++)
#pragma unroll
        for (int j = 0; j < 4; j++) acc[i][j] = 0.f;

    for (int k0 = 0; k0 < EMB; k0 += 64) {
        __syncthreads();
        // stage B chunk [64 k][64 n] row-major (b128, bank-uniform)
#pragma unroll
        for (int i = 0; i < 4; i++) {
            int r = ty + 16 * i;
            *(float4*)&Bs[r][ldc] =
                *(const float4*)&W[(size_t)(k0 + r) * EMB + bx * 64 + ldc];
        }
        __syncthreads();
#pragma unroll 4
        for (int k4 = 0; k4 < 16; k4++) {
            const int kk = k4 * 4;
            // A frags from GLOBAL: 4 rows x 4 k (4 distinct 16B addrs/wave)
            float a[4][4];
            *(float4*)&a[0][0] = *(const float4*)&a0[k0 + kk];
            *(float4*)&a[1][0] = *(const float4*)&a1[k0 + kk];
            *(float4*)&a[2][0] = *(const float4*)&a2r[k0 + kk];
            *(float4*)&a[3][0] = *(const float4*)&a3[k0 + kk];
#pragma unroll
            for (int u = 0; u < 4; u++) {
                float b[4];
                *(float4*)b = *(const float4*)&Bs[kk + u][ldc];
#pragma unroll
                for (int i = 0; i < 4; i++)
#pragma unroll
                    for (int j = 0; j < 4; j++)
                        acc[i][j] = fmaf(a[i][u], b[j], acc[i][j]);
            }
        }
    }

#pragma unroll
    for (int i = 0; i < 4; i++) {
        int m = by * 64 + ty * 4 + i;
        int b2 = m / L_SEQ, l = m % L_SEQ;
        float o[4];
#pragma unroll
        for (int j = 0; j < 4; j++) o[j] = acc[i][j] + bias[bx * 64 + tx * 4 + j];
        *(float4*)&dst[((size_t)(b2 * NH + bx) * L_SEQ + l) * DH + tx * 4] = *(float4*)o;
    }
}

// ---------------------------------------------------------------------------
// K2 v2 (round-14): K-chunk c+1 register-prefetched during compute of c.
// XCD-chunked bijective swizzle kept from round-13.
// ---------------------------------------------------------------------------
__global__ __launch_bounds__(256) void k2_stats(
    const float* __restrict__ qw, const float* __restrict__ kw,
    const float* __restrict__ mask, float* __restrict__ part)
{
    __shared__ float k_lds[64 * 64];
    __shared__ float m_lds[64];
    const int tid = threadIdx.x;
    const int lane = tid & 63, w = tid >> 6;
    const int qr = lane >> 3, d = lane & 7;
    const int lb = (blockIdx.x & 7) * 144 + (blockIdx.x >> 3);
    const int kq = lb & 3;
    const int t2 = lb >> 2;             // 0..287
    const int bh = t2 / 12;
    const int q0 = (t2 % 12) * 64;
    const int b = bh / NH;
    const int qw0 = q0 + w * 16;

    float qf[2][8];
#pragma unroll
    for (int qq = 0; qq < 2; qq++) {
        const float* qp = &qw[((size_t)bh * L_SEQ + qw0 + qr + qq * 8) * DH + d * 8];
        *(float4*)&qf[qq][0] = *(const float4*)qp;
        *(float4*)&qf[qq][4] = *(const float4*)(qp + 4);
    }
    float S[2] = {0.f, 0.f}, T2[2] = {0.f, 0.f}, SL[2] = {0.f, 0.f};
    float M[2] = {-1e30f, -1e30f};

    const int kb0 = kq * 192;

    // prefetch chunk 0
    float4 pk[4];
    float pm = 0.f;
    {
        const float* src = &kw[((size_t)bh * L_SEQ + kb0) * DH];
#pragma unroll
        for (int i = 0; i < 4; i++) pk[i] = *(const float4*)&src[(tid + 256 * i) * 4];
        if (tid < 64) pm = mask[b * L_SEQ + kb0 + tid];
    }

    for (int c = 0; c < 3; c++) {
        __syncthreads();
        {
#pragma unroll
            for (int i = 0; i < 4; i++)
                *(float4*)&k_lds[(tid + 256 * i) * 4] = pk[i];
            if (tid < 64) m_lds[tid] = pm;
        }
        __syncthreads();
        if (c < 2) {
            const int kb = kb0 + (c + 1) * 64;
            const float* src = &kw[((size_t)bh * L_SEQ + kb) * DH];
#pragma unroll
            for (int i = 0; i < 4; i++) pk[i] = *(const float4*)&src[(tid + 256 * i) * 4];
            if (tid < 64) pm = mask[b * L_SEQ + kb + tid];
        }
#pragma unroll 4
        for (int kk = 0; kk < 64; kk++) {
            float kv[8];
            *(float4*)&kv[0] = *(const float4*)&k_lds[kk * 64 + d * 8];
            *(float4*)&kv[4] = *(const float4*)&k_lds[kk * 64 + d * 8 + 4];
            float mval = m_lds[kk];
#pragma unroll
            for (int qq = 0; qq < 2; qq++) {
                float s = 0.f;
#pragma unroll
                for (int t = 0; t < 8; t++) s = fmaf(qf[qq][t], kv[t], s);
                s = fmaf(s, RSQRT8, mval);
                float e = __expf(s);
                S[qq] += e;
                T2[qq] = fmaf(e, e, T2[qq]);
                SL[qq] = fmaf(s, e, SL[qq]);
                M[qq] = fmaxf(M[qq], s);
            }
        }
    }
#pragma unroll
    for (int qq = 0; qq < 2; qq++) {
        int q = qw0 + qr + qq * 8;
        size_t base = (size_t)(bh * 8 + d) * 16;
        part[(base + 0 + kq) * 768 + q] = S[qq];
        part[(base + 4 + kq) * 768 + q] = T2[qq];
        part[(base + 8 + kq) * 768 + q] = SL[qq];
        part[(base + 12 + kq) * 768 + q] = M[qq];
    }
}

// ---------------------------------------------------------------------------
// K3a: per-(b,d,h) combine of k-quarters -> row stats -> linv + stat sums.
// Stores 1/S in [bh][q][d] layout so k45 fetches all 8 d-values for a q row
// with one uniform (scalar) 8-float load.
// ---------------------------------------------------------------------------
__global__ __launch_bounds__(256) void k3_reduce(
    const float* __restrict__ part, float* __restrict__ linv,
    float* __restrict__ part2)
{
    const int bdh = blockIdx.x;         // ((b*8+d)*12+h)
    const int bd = bdh / 12, h = bdh % 12;
    const int b = bd >> 3, d = bd & 7;
    const int bh = b * NH + h;
    const int tid = threadIdx.x;
    const int lane = tid & 63, wave = tid >> 6;
    const size_t base = (size_t)(bh * 8 + d) * 16;
    float acc[4] = {0.f, 0.f, 0.f, 0.f};

    for (int q = tid; q < 768; q += 256) {
        float Sv = 0.f, T2v = 0.f, SLv = 0.f, Mv = -1e30f;
#pragma unroll
        for (int kq = 0; kq < 4; kq++) {
            Sv  += part[(base + 0 + kq) * 768 + q];
            T2v += part[(base + 4 + kq) * 768 + q];
            SLv += part[(base + 8 + kq) * 768 + q];
            Mv = fmaxf(Mv, part[(base + 12 + kq) * 768 + q]);
        }
        float inv = 1.0f / Sv;
        linv[((size_t)bh * 768 + q) * 8 + d] = inv;
        float hhi = T2v * inv * inv;
        float maxp = __expf(Mv) * inv;
        float ent = __logf(Sv) - SLv * inv;
        float var = (hhi - (1.0f / 768.0f)) * (1.0f / 767.0f);
        acc[0] += var; acc[1] += maxp; acc[2] += ent; acc[3] += hhi;
    }
    __shared__ float red[4][4];
#pragma unroll
    for (int st = 0; st < 4; st++) {
        float a = acc[st];
#pragma unroll
        for (int off = 32; off > 0; off >>= 1) a += __shfl_xor(a, off, 64);
        acc[st] = a;
    }
    if (lane == 0) {
#pragma unroll
        for (int st = 0; st < 4; st++) red[wave][st] = acc[st];
    }
    __syncthreads();
    if (tid == 0) {
#pragma unroll
        for (int st = 0; st < 4; st++)
            part2[(size_t)(bd * 12 + h) * 4 + st] =
                red[0][st] + red[1][st] + red[2][st] + red[3][st];
    }
}

// ---------------------------------------------------------------------------
// K3b: sum over h, min-max norm over d, softmax(2.5*score) -> weights[b][d].
// ---------------------------------------------------------------------------
__global__ __launch_bounds__(64) void k3_weights(
    const float* __restrict__ part2, float* __restrict__ wgt)
{
    __shared__ float stats_l[64];       // [b][d][st]
    const int tid = threadIdx.x;
    {
        const int bd = tid >> 2, st = tid & 3;
        float s = 0.f;
#pragma unroll
        for (int h = 0; h < 12; h++) s += part2[(size_t)(bd * 12 + h) * 4 + st];
        stats_l[tid] = s * (1.0f / 9216.0f);
    }
    __syncthreads();
    if (tid == 0) {
        for (int b = 0; b < BATCH; b++) {
            float v[4][8];
            for (int st = 0; st < 4; st++)
                for (int d = 0; d < 8; d++) v[st][d] = stats_l[(b * 8 + d) * 4 + st];
            float nrm[4][8];
            for (int st = 0; st < 4; st++) {
                float mn = v[st][0], mx = v[st][0];
                for (int d = 1; d < 8; d++) { mn = fminf(mn, v[st][d]); mx = fmaxf(mx, v[st][d]); }
                float rng = fmaxf(mx - mn, 1e-12f);
                for (int d = 0; d < 8; d++) nrm[st][d] = (v[st][d] - mn) / rng;
            }
            float sc[8];
            for (int d = 0; d < 8; d++)
                sc[d] = 0.5f * nrm[0][d] + 0.3f * nrm[1][d] + 0.2f * nrm[3][d] - 0.4f * nrm[2][d];
            float m = 2.5f * sc[0];
            for (int d = 1; d < 8; d++) m = fmaxf(m, 2.5f * sc[d]);
            float e8[8]; float ssum = 0.f;
            for (int d = 0; d < 8; d++) { e8[d] = __expf(2.5f * sc[d] - m); ssum += e8[d]; }
            for (int d = 0; d < 8; d++) wgt[b * ND + d] = e8[d] / ssum;
        }
    }
}

// ---------------------------------------------------------------------------
// K45 v6 (round-13, UNCHANGED): pipe-split a4+ctx with register-resident K.
// ---------------------------------------------------------------------------
__global__ __launch_bounds__(256, 4) void k45_fused(
    const float* __restrict__ qw, const float* __restrict__ kw,
    const float* __restrict__ vw, const float* __restrict__ mask,
    const float* __restrict__ linv, const float* __restrict__ wgt,
    float* __restrict__ out_a4, float* __restrict__ out_ctx)
{
    // per-wave region: a4T [k 64][20 pad] during chunks; ctx [q 16][68 pad] at end
    __shared__ float smem[4][64 * 20];
    const int tid = threadIdx.x;
    const int lane = tid & 63, w = tid >> 6;
    // XCD-chunked bijective swizzle: logical blocks 0..143 -> XCD0, etc.
    const int lb = (blockIdx.x & 7) * 144 + (blockIdx.x >> 3);
    const int bh = lb / 48;                 // 0..23
    const int q0 = (lb % 48) * 16;
    const int b = bh / NH, h = bh % NH;
    // phase-B lane mapping: 4 q rows (qg*4..+3) x 4 dh cols (dhl*4..+3)
    const int qg = lane >> 4;               // 0..3
    const int dhl = lane & 15;              // 0..15

    const float* kbase = &kw[(size_t)bh * L_SEQ * DH];
    const float* vbase = &vw[(size_t)bh * L_SEQ * DH];
    const float* qtile = &qw[((size_t)bh * L_SEQ + q0) * DH];   // block-uniform rows
    const float* ltile = &linv[((size_t)bh * L_SEQ + q0) * 8];

    // wgt[b][0..7]: broadcast
    float wv[8];
#pragma unroll
    for (int d = 0; d < 8; d++) wv[d] = wgt[b * ND + d];

    float acc[4][4];                        // ctx partial: 4 q rows x 4 dh
#pragma unroll
    for (int i = 0; i < 4; i++)
#pragma unroll
        for (int j = 0; j < 4; j++) acc[i][j] = 0.f;

    float* sm = &smem[w][0];

    for (int c = 0; c < 3; c++) {
        const int kb = (w * 3 + c) * 64;    // this wave's k chunk
        const int krow = kb + lane;

        // K row -> VGPRs (must stay resident: see header comment)
        float kv[64];
        {
            const float* kp = &kbase[(size_t)krow * DH];
#pragma unroll
            for (int t = 0; t < 16; t++)
                *(float4*)&kv[t * 4] = *(const float4*)&kp[t * 4];
        }
        const float mval = mask[b * L_SEQ + krow];

        // ---- Phase A: a4(q, krow), one q at a time, K register-resident ----
#pragma unroll 2
        for (int q = 0; q < 16; q++) {
            const float* qp = &qtile[(size_t)q * DH];
            const float* lp = &ltile[(size_t)q * 8];
            float sd[8];
#pragma unroll
            for (int d = 0; d < 8; d++) sd[d] = 0.f;
#pragma unroll
            for (int d = 0; d < 8; d++)
#pragma unroll
                for (int t = 0; t < 8; t++)
                    sd[d] = fmaf(qp[d * 8 + t], kv[d * 8 + t], sd[d]);
            float a4v = 0.f;
#pragma unroll
            for (int d = 0; d < 8; d++) {
                float sv = fmaf(sd[d], RSQRT8, mval);
                a4v = fmaf(wv[d] * lp[d], __expf(sv), a4v);
            }
            out_a4[((size_t)bh * L_SEQ + q0 + q) * L_SEQ + krow] = a4v;
            sm[lane * 20 + q] = a4v;        // a4T[k][q] (wave-private)
        }

        // ---- Phase B: ctx += a4T @ V over this chunk (k ascending) ----
        const float* vrow = &vbase[(size_t)kb * DH + dhl * 4];
#pragma unroll 8
        for (int k = 0; k < 64; k++) {
            float av[4];
            *(float4*)av = *(const float4*)&sm[k * 20 + qg * 4];
            float4 vv = *(const float4*)&vrow[(size_t)k * DH];
#pragma unroll
            for (int i = 0; i < 4; i++) {
                acc[i][0] = fmaf(av[i], vv.x, acc[i][0]);
                acc[i][1] = fmaf(av[i], vv.y, acc[i][1]);
                acc[i][2] = fmaf(av[i], vv.z, acc[i][2]);
                acc[i][3] = fmaf(av[i], vv.w, acc[i][3]);
            }
        }
    }

    // ---- ctx k-partials -> LDS (alias a4T region), block-reduce over waves ----
#pragma unroll
    for (int i = 0; i < 4; i++)
        *(float4*)&sm[(qg * 4 + i) * 68 + dhl * 4] = *(float4*)&acc[i][0];
    __syncthreads();
    {
        const int q = tid >> 4;             // 0..15
        const int dh4 = (tid & 15) * 4;     // 0..60
        float r[4] = {0.f, 0.f, 0.f, 0.f};
#pragma unroll
        for (int ww = 0; ww < 4; ww++) {
            const float* s2 = &smem[ww][q * 68 + dh4];
#pragma unroll
            for (int j = 0; j < 4; j++) r[j] += s2[j];
        }
        *(float4*)&out_ctx[((size_t)b * L_SEQ + q0 + q) * EMB + h * DH + dh4] =
            *(float4*)r;
    }
}

// ---------------------------------------------------------------------------
extern "C" void kernel_launch(void* const* d_in, const int* in_sizes, int n_in,
                              void* d_out, int out_size, void* d_ws, size_t ws_size,
                              hipStream_t stream)
{
    const float* hs   = (const float*)d_in[0];
    const float* mask = (const float*)d_in[1];
    const float* Wq   = (const float*)d_in[2];
    const float* bq   = (const float*)d_in[3];
    const float* Wk   = (const float*)d_in[4];
    const float* bk   = (const float*)d_in[5];
    const float* Wv   = (const float*)d_in[6];
    const float* bv   = (const float*)d_in[7];

    float* ws = (float*)d_ws;
    float* qw    = ws + OFF_Q;
    float* kw    = ws + OFF_K;
    float* vw    = ws + OFF_V;
    float* linv  = ws + OFF_L;
    float* part  = ws + OFF_PART;
    float* part2 = ws + OFF_P2;
    float* wgt   = ws + OFF_W;

    float* out_ctx = (float*)d_out;                                  // [B, L, 768]
    float* out_a4  = (float*)d_out + (size_t)BATCH * L_SEQ * EMB;    // [B, H, L, L]

    k1_qkv<<<dim3(12, 24, 3), 256, 0, stream>>>(hs, Wq, bq, Wk, bk, Wv, bv, qw, kw, vw);
    k2_stats<<<dim3(1152), 256, 0, stream>>>(qw, kw, mask, part);
    k3_reduce<<<dim3(192), 256, 0, stream>>>(part, linv, part2);
    k3_weights<<<dim3(1), 64, 0, stream>>>(part2, wgt);
    k45_fused<<<dim3(1152), 256, 0, stream>>>(qw, kw, vw, mask, linv, wgt,
                                              out_a4, out_ctx);
}

// Round 12
// 332.364 us; speedup vs baseline: 2.3021x; 1.0143x over previous
//
#include <hip/hip_runtime.h>

// Problem constants (fixed by reference setup_inputs)
#define BATCH 2
#define L_SEQ 768
#define NH 12
#define DH 64
#define ND 8
#define EMB 768
#define RSQRT8 0.35355339059327373f

// ws layout (floats). Total 6,046,480 floats = 24.2 MB -- UNCHANGED footprint.
#define OFF_Q    0
#define OFF_K    1179648
#define OFF_V    2359296
#define OFF_L    3538944   // linv[bh][q][d] = 1/S : 147456
#define OFF_PART 3686400   // partial stats [bh*8+d][st*4+kq][q]: 2359296
#define OFF_P2   6045696   // per-(b,d,h) stat sums [bd][h][st]: 768
#define OFF_W    6046464   // weights [b][d]: 16

// ---------------------------------------------------------------------------
// K1 v7 (round-19): hybrid (B in LDS, A from global) + K-SPLIT for occupancy.
// ROUND-18 LESSON (rocprof): hybrid verified (LDS 17408, no spill, DS
// halved) but 121us at Occupancy 28.7% -- grid 864 = 3.375 blk/CU caps
// waves at 13.5/CU; ~2.3 waves/SIMD can't hide the A-load L1 latency
// (VALUBusy 37.6%). The structure is right; the GRID is the limit.
// FIX: each block does a K-HALF (384) of a 64x64 tile -> grid 1728 =
// 6.75 blk/CU = 27 waves/CU (84%). Halves write LINEAR partials into the
// dead out_a4 region of d_out (14.16M floats >= 7.08M needed; ws footprint
// unchanged -- round-9 container-fault lesson). k1b_combine adds halves +
// bias and scatters to [b][h][l][64] (42MB, ~7us). Per-half FMA order
// k-ascending unchanged; final = h0+h1+bias (~1e-6 rel vs tolerance 4.9e-4).
// Verification: Occupancy >= 60%, k1 dur 55-65us, k1b ~7us.
// ---------------------------------------------------------------------------
__global__ __launch_bounds__(256) void k1_qkv(
    const float* __restrict__ hs,
    const float* __restrict__ Wq, const float* __restrict__ Wk,
    const float* __restrict__ Wv, float* __restrict__ scr)
{
    __shared__ float Bs[64][68];
    const int tid = threadIdx.x;
    const int tx = tid & 15, ty = tid >> 4;
    const int bx = blockIdx.x, by = blockIdx.y;
    const int gz = blockIdx.z;               // 0..5
    const int p = gz >> 1, kh = gz & 1;      // proj, k-half
    const float* W = (p == 0) ? Wq : (p == 1 ? Wk : Wv);

    const int ldc = tx * 4;
    const float* a0  = &hs[(size_t)(by * 64 + ty * 4 + 0) * EMB];
    const float* a1  = &hs[(size_t)(by * 64 + ty * 4 + 1) * EMB];
    const float* a2r = &hs[(size_t)(by * 64 + ty * 4 + 2) * EMB];
    const float* a3  = &hs[(size_t)(by * 64 + ty * 4 + 3) * EMB];

    float acc[4][4];
#pragma unroll
    for (int i = 0; i < 4; i++)
#pragma unroll
        for (int j = 0; j < 4; j++) acc[i][j] = 0.f;

    for (int c = 0; c < 6; c++) {
        const int k0 = kh * 384 + c * 64;
        __syncthreads();
        // stage B chunk [64 k][64 n] row-major (b128, bank-uniform)
#pragma unroll
        for (int i = 0; i < 4; i++) {
            int r = ty + 16 * i;
            *(float4*)&Bs[r][ldc] =
                *(const float4*)&W[(size_t)(k0 + r) * EMB + bx * 64 + ldc];
        }
        __syncthreads();
#pragma unroll 4
        for (int k4 = 0; k4 < 16; k4++) {
            const int kk = k4 * 4;
            float a[4][4];
            *(float4*)&a[0][0] = *(const float4*)&a0[k0 + kk];
            *(float4*)&a[1][0] = *(const float4*)&a1[k0 + kk];
            *(float4*)&a[2][0] = *(const float4*)&a2r[k0 + kk];
            *(float4*)&a[3][0] = *(const float4*)&a3[k0 + kk];
#pragma unroll
            for (int u = 0; u < 4; u++) {
                float b[4];
                *(float4*)b = *(const float4*)&Bs[kk + u][ldc];
#pragma unroll
                for (int i = 0; i < 4; i++)
#pragma unroll
                    for (int j = 0; j < 4; j++)
                        acc[i][j] = fmaf(a[i][u], b[j], acc[i][j]);
            }
        }
    }

    // linear partial store: scr[(kh*3+p)][m][n]  (coalesced)
    float* sp = &scr[(size_t)(kh * 3 + p) * 1179648];
#pragma unroll
    for (int i = 0; i < 4; i++) {
        const int m = by * 64 + ty * 4 + i;
        *(float4*)&sp[(size_t)m * 768 + bx * 64 + tx * 4] = *(float4*)&acc[i][0];
    }
}

// ---------------------------------------------------------------------------
// K1b: combine K-halves + bias, scatter to [b][h][l][64]. 42MB ~ 7us.
// ---------------------------------------------------------------------------
__global__ __launch_bounds__(256) void k1b_combine(
    const float* __restrict__ scr,
    const float* __restrict__ bq, const float* __restrict__ bk,
    const float* __restrict__ bvp,
    float* __restrict__ qw, float* __restrict__ kw, float* __restrict__ vw)
{
    const size_t g = (size_t)blockIdx.x * 256 + threadIdx.x;  // 0..884735
    const size_t i4 = g * 4;
    const int p = (int)(i4 / 1179648);
    const int r = (int)(i4 % 1179648);
    const int m = r / 768, n = r % 768;

    float4 x0 = *(const float4*)&scr[(size_t)p * 1179648 + r];
    float4 x1 = *(const float4*)&scr[(size_t)(3 + p) * 1179648 + r];
    const float* bias = (p == 0) ? bq : (p == 1 ? bk : bvp);
    float o[4];
    o[0] = x0.x + x1.x + bias[n + 0];
    o[1] = x0.y + x1.y + bias[n + 1];
    o[2] = x0.z + x1.z + bias[n + 2];
    o[3] = x0.w + x1.w + bias[n + 3];

    float* dst = (p == 0) ? qw : (p == 1 ? kw : vw);
    const int b2 = m / L_SEQ, l = m % L_SEQ;
    const int h = n >> 6, dh = n & 63;
    *(float4*)&dst[((size_t)(b2 * NH + h) * L_SEQ + l) * DH + dh] = *(float4*)o;
}

// ---------------------------------------------------------------------------
// K2 v2 (round-14): K-chunk c+1 register-prefetched during compute of c.
// XCD-chunked bijective swizzle kept from round-13.
// ---------------------------------------------------------------------------
__global__ __launch_bounds__(256) void k2_stats(
    const float* __restrict__ qw, const float* __restrict__ kw,
    const float* __restrict__ mask, float* __restrict__ part)
{
    __shared__ float k_lds[64 * 64];
    __shared__ float m_lds[64];
    const int tid = threadIdx.x;
    const int lane = tid & 63, w = tid >> 6;
    const int qr = lane >> 3, d = lane & 7;
    const int lb = (blockIdx.x & 7) * 144 + (blockIdx.x >> 3);
    const int kq = lb & 3;
    const int t2 = lb >> 2;             // 0..287
    const int bh = t2 / 12;
    const int q0 = (t2 % 12) * 64;
    const int b = bh / NH;
    const int qw0 = q0 + w * 16;

    float qf[2][8];
#pragma unroll
    for (int qq = 0; qq < 2; qq++) {
        const float* qp = &qw[((size_t)bh * L_SEQ + qw0 + qr + qq * 8) * DH + d * 8];
        *(float4*)&qf[qq][0] = *(const float4*)qp;
        *(float4*)&qf[qq][4] = *(const float4*)(qp + 4);
    }
    float S[2] = {0.f, 0.f}, T2[2] = {0.f, 0.f}, SL[2] = {0.f, 0.f};
    float M[2] = {-1e30f, -1e30f};

    const int kb0 = kq * 192;

    // prefetch chunk 0
    float4 pk[4];
    float pm = 0.f;
    {
        const float* src = &kw[((size_t)bh * L_SEQ + kb0) * DH];
#pragma unroll
        for (int i = 0; i < 4; i++) pk[i] = *(const float4*)&src[(tid + 256 * i) * 4];
        if (tid < 64) pm = mask[b * L_SEQ + kb0 + tid];
    }

    for (int c = 0; c < 3; c++) {
        __syncthreads();
        {
#pragma unroll
            for (int i = 0; i < 4; i++)
                *(float4*)&k_lds[(tid + 256 * i) * 4] = pk[i];
            if (tid < 64) m_lds[tid] = pm;
        }
        __syncthreads();
        if (c < 2) {
            const int kb = kb0 + (c + 1) * 64;
            const float* src = &kw[((size_t)bh * L_SEQ + kb) * DH];
#pragma unroll
            for (int i = 0; i < 4; i++) pk[i] = *(const float4*)&src[(tid + 256 * i) * 4];
            if (tid < 64) pm = mask[b * L_SEQ + kb + tid];
        }
#pragma unroll 4
        for (int kk = 0; kk < 64; kk++) {
            float kv[8];
            *(float4*)&kv[0] = *(const float4*)&k_lds[kk * 64 + d * 8];
            *(float4*)&kv[4] = *(const float4*)&k_lds[kk * 64 + d * 8 + 4];
            float mval = m_lds[kk];
#pragma unroll
            for (int qq = 0; qq < 2; qq++) {
                float s = 0.f;
#pragma unroll
                for (int t = 0; t < 8; t++) s = fmaf(qf[qq][t], kv[t], s);
                s = fmaf(s, RSQRT8, mval);
                float e = __expf(s);
                S[qq] += e;
                T2[qq] = fmaf(e, e, T2[qq]);
                SL[qq] = fmaf(s, e, SL[qq]);
                M[qq] = fmaxf(M[qq], s);
            }
        }
    }
#pragma unroll
    for (int qq = 0; qq < 2; qq++) {
        int q = qw0 + qr + qq * 8;
        size_t base = (size_t)(bh * 8 + d) * 16;
        part[(base + 0 + kq) * 768 + q] = S[qq];
        part[(base + 4 + kq) * 768 + q] = T2[qq];
        part[(base + 8 + kq) * 768 + q] = SL[qq];
        part[(base + 12 + kq) * 768 + q] = M[qq];
    }
}

// ---------------------------------------------------------------------------
// K3a: per-(b,d,h) combine of k-quarters -> row stats -> linv + stat sums.
// Stores 1/S in [bh][q][d] layout so k45 fetches all 8 d-values for a q row
// with one uniform (scalar) 8-float load.
// ---------------------------------------------------------------------------
__global__ __launch_bounds__(256) void k3_reduce(
    const float* __restrict__ part, float* __restrict__ linv,
    float* __restrict__ part2)
{
    const int bdh = blockIdx.x;         // ((b*8+d)*12+h)
    const int bd = bdh / 12, h = bdh % 12;
    const int b = bd >> 3, d = bd & 7;
    const int bh = b * NH + h;
    const int tid = threadIdx.x;
    const int lane = tid & 63, wave = tid >> 6;
    const size_t base = (size_t)(bh * 8 + d) * 16;
    float acc[4] = {0.f, 0.f, 0.f, 0.f};

    for (int q = tid; q < 768; q += 256) {
        float Sv = 0.f, T2v = 0.f, SLv = 0.f, Mv = -1e30f;
#pragma unroll
        for (int kq = 0; kq < 4; kq++) {
            Sv  += part[(base + 0 + kq) * 768 + q];
            T2v += part[(base + 4 + kq) * 768 + q];
            SLv += part[(base + 8 + kq) * 768 + q];
            Mv = fmaxf(Mv, part[(base + 12 + kq) * 768 + q]);
        }
        float inv = 1.0f / Sv;
        linv[((size_t)bh * 768 + q) * 8 + d] = inv;
        float hhi = T2v * inv * inv;
        float maxp = __expf(Mv) * inv;
        float ent = __logf(Sv) - SLv * inv;
        float var = (hhi - (1.0f / 768.0f)) * (1.0f / 767.0f);
        acc[0] += var; acc[1] += maxp; acc[2] += ent; acc[3] += hhi;
    }
    __shared__ float red[4][4];
#pragma unroll
    for (int st = 0; st < 4; st++) {
        float a = acc[st];
#pragma unroll
        for (int off = 32; off > 0; off >>= 1) a += __shfl_xor(a, off, 64);
        acc[st] = a;
    }
    if (lane == 0) {
#pragma unroll
        for (int st = 0; st < 4; st++) red[wave][st] = acc[st];
    }
    __syncthreads();
    if (tid == 0) {
#pragma unroll
        for (int st = 0; st < 4; st++)
            part2[(size_t)(bd * 12 + h) * 4 + st] =
                red[0][st] + red[1][st] + red[2][st] + red[3][st];
    }
}

// ---------------------------------------------------------------------------
// K3b: sum over h, min-max norm over d, softmax(2.5*score) -> weights[b][d].
// ---------------------------------------------------------------------------
__global__ __launch_bounds__(64) void k3_weights(
    const float* __restrict__ part2, float* __restrict__ wgt)
{
    __shared__ float stats_l[64];       // [b][d][st]
    const int tid = threadIdx.x;
    {
        const int bd = tid >> 2, st = tid & 3;
        float s = 0.f;
#pragma unroll
        for (int h = 0; h < 12; h++) s += part2[(size_t)(bd * 12 + h) * 4 + st];
        stats_l[tid] = s * (1.0f / 9216.0f);
    }
    __syncthreads();
    if (tid == 0) {
        for (int b = 0; b < BATCH; b++) {
            float v[4][8];
            for (int st = 0; st < 4; st++)
                for (int d = 0; d < 8; d++) v[st][d] = stats_l[(b * 8 + d) * 4 + st];
            float nrm[4][8];
            for (int st = 0; st < 4; st++) {
                float mn = v[st][0], mx = v[st][0];
                for (int d = 1; d < 8; d++) { mn = fminf(mn, v[st][d]); mx = fmaxf(mx, v[st][d]); }
                float rng = fmaxf(mx - mn, 1e-12f);
                for (int d = 0; d < 8; d++) nrm[st][d] = (v[st][d] - mn) / rng;
            }
            float sc[8];
            for (int d = 0; d < 8; d++)
                sc[d] = 0.5f * nrm[0][d] + 0.3f * nrm[1][d] + 0.2f * nrm[3][d] - 0.4f * nrm[2][d];
            float m = 2.5f * sc[0];
            for (int d = 1; d < 8; d++) m = fmaxf(m, 2.5f * sc[d]);
            float e8[8]; float ssum = 0.f;
            for (int d = 0; d < 8; d++) { e8[d] = __expf(2.5f * sc[d] - m); ssum += e8[d]; }
            for (int d = 0; d < 8; d++) wgt[b * ND + d] = e8[d] / ssum;
        }
    }
}

// ---------------------------------------------------------------------------
// K45 v6 (round-13, UNCHANGED): pipe-split a4+ctx with register-resident K.
// ---------------------------------------------------------------------------
__global__ __launch_bounds__(256, 4) void k45_fused(
    const float* __restrict__ qw, const float* __restrict__ kw,
    const float* __restrict__ vw, const float* __restrict__ mask,
    const float* __restrict__ linv, const float* __restrict__ wgt,
    float* __restrict__ out_a4, float* __restrict__ out_ctx)
{
    // per-wave region: a4T [k 64][20 pad] during chunks; ctx [q 16][68 pad] at end
    __shared__ float smem[4][64 * 20];
    const int tid = threadIdx.x;
    const int lane = tid & 63, w = tid >> 6;
    // XCD-chunked bijective swizzle: logical blocks 0..143 -> XCD0, etc.
    const int lb = (blockIdx.x & 7) * 144 + (blockIdx.x >> 3);
    const int bh = lb / 48;                 // 0..23
    const int q0 = (lb % 48) * 16;
    const int b = bh / NH, h = bh % NH;
    // phase-B lane mapping: 4 q rows (qg*4..+3) x 4 dh cols (dhl*4..+3)
    const int qg = lane >> 4;               // 0..3
    const int dhl = lane & 15;              // 0..15

    const float* kbase = &kw[(size_t)bh * L_SEQ * DH];
    const float* vbase = &vw[(size_t)bh * L_SEQ * DH];
    const float* qtile = &qw[((size_t)bh * L_SEQ + q0) * DH];   // block-uniform rows
    const float* ltile = &linv[((size_t)bh * L_SEQ + q0) * 8];

    // wgt[b][0..7]: broadcast
    float wv[8];
#pragma unroll
    for (int d = 0; d < 8; d++) wv[d] = wgt[b * ND + d];

    float acc[4][4];                        // ctx partial: 4 q rows x 4 dh
#pragma unroll
    for (int i = 0; i < 4; i++)
#pragma unroll
        for (int j = 0; j < 4; j++) acc[i][j] = 0.f;

    float* sm = &smem[w][0];

    for (int c = 0; c < 3; c++) {
        const int kb = (w * 3 + c) * 64;    // this wave's k chunk
        const int krow = kb + lane;

        // K row -> VGPRs (must stay resident: see header comment)
        float kv[64];
        {
            const float* kp = &kbase[(size_t)krow * DH];
#pragma unroll
            for (int t = 0; t < 16; t++)
                *(float4*)&kv[t * 4] = *(const float4*)&kp[t * 4];
        }
        const float mval = mask[b * L_SEQ + krow];

        // ---- Phase A: a4(q, krow), one q at a time, K register-resident ----
#pragma unroll 2
        for (int q = 0; q < 16; q++) {
            const float* qp = &qtile[(size_t)q * DH];
            const float* lp = &ltile[(size_t)q * 8];
            float sd[8];
#pragma unroll
            for (int d = 0; d < 8; d++) sd[d] = 0.f;
#pragma unroll
            for (int d = 0; d < 8; d++)
#pragma unroll
                for (int t = 0; t < 8; t++)
                    sd[d] = fmaf(qp[d * 8 + t], kv[d * 8 + t], sd[d]);
            float a4v = 0.f;
#pragma unroll
            for (int d = 0; d < 8; d++) {
                float sv = fmaf(sd[d], RSQRT8, mval);
                a4v = fmaf(wv[d] * lp[d], __expf(sv), a4v);
            }
            out_a4[((size_t)bh * L_SEQ + q0 + q) * L_SEQ + krow] = a4v;
            sm[lane * 20 + q] = a4v;        // a4T[k][q] (wave-private)
        }

        // ---- Phase B: ctx += a4T @ V over this chunk (k ascending) ----
        const float* vrow = &vbase[(size_t)kb * DH + dhl * 4];
#pragma unroll 8
        for (int k = 0; k < 64; k++) {
            float av[4];
            *(float4*)av = *(const float4*)&sm[k * 20 + qg * 4];
            float4 vv = *(const float4*)&vrow[(size_t)k * DH];
#pragma unroll
            for (int i = 0; i < 4; i++) {
                acc[i][0] = fmaf(av[i], vv.x, acc[i][0]);
                acc[i][1] = fmaf(av[i], vv.y, acc[i][1]);
                acc[i][2] = fmaf(av[i], vv.z, acc[i][2]);
                acc[i][3] = fmaf(av[i], vv.w, acc[i][3]);
            }
        }
    }

    // ---- ctx k-partials -> LDS (alias a4T region), block-reduce over waves ----
#pragma unroll
    for (int i = 0; i < 4; i++)
        *(float4*)&sm[(qg * 4 + i) * 68 + dhl * 4] = *(float4*)&acc[i][0];
    __syncthreads();
    {
        const int q = tid >> 4;             // 0..15
        const int dh4 = (tid & 15) * 4;     // 0..60
        float r[4] = {0.f, 0.f, 0.f, 0.f};
#pragma unroll
        for (int ww = 0; ww < 4; ww++) {
            const float* s2 = &smem[ww][q * 68 + dh4];
#pragma unroll
            for (int j = 0; j < 4; j++) r[j] += s2[j];
        }
        *(float4*)&out_ctx[((size_t)b * L_SEQ + q0 + q) * EMB + h * DH + dh4] =
            *(float4*)r;
    }
}

// ---------------------------------------------------------------------------
extern "C" void kernel_launch(void* const* d_in, const int* in_sizes, int n_in,
                              void* d_out, int out_size, void* d_ws, size_t ws_size,
                              hipStream_t stream)
{
    const float* hs   = (const float*)d_in[0];
    const float* mask = (const float*)d_in[1];
    const float* Wq   = (const float*)d_in[2];
    const float* bq   = (const float*)d_in[3];
    const float* Wk   = (const float*)d_in[4];
    const float* bk   = (const float*)d_in[5];
    const float* Wv   = (const float*)d_in[6];
    const float* bv   = (const float*)d_in[7];

    float* ws = (float*)d_ws;
    float* qw    = ws + OFF_Q;
    float* kw    = ws + OFF_K;
    float* vw    = ws + OFF_V;
    float* linv  = ws + OFF_L;
    float* part  = ws + OFF_PART;
    float* part2 = ws + OFF_P2;
    float* wgt   = ws + OFF_W;

    float* out_ctx = (float*)d_out;                                  // [B, L, 768]
    float* out_a4  = (float*)d_out + (size_t)BATCH * L_SEQ * EMB;    // [B, H, L, L]
    float* scr     = out_a4;   // k1 partial scratch: 7.08M <= 14.16M floats,
                               // dead until k45 overwrites it

    k1_qkv<<<dim3(12, 24, 6), 256, 0, stream>>>(hs, Wq, Wk, Wv, scr);
    k1b_combine<<<dim3(3456), 256, 0, stream>>>(scr, bq, bk, bv, qw, kw, vw);
    k2_stats<<<dim3(1152), 256, 0, stream>>>(qw, kw, mask, part);
    k3_reduce<<<dim3(192), 256, 0, stream>>>(part, linv, part2);
    k3_weights<<<dim3(1), 64, 0, stream>>>(part2, wgt);
    k45_fused<<<dim3(1152), 256, 0, stream>>>(qw, kw, vw, mask, linv, wgt,
                                              out_a4, out_ctx);
}